// Round 1
// baseline (66838.147 us; speedup 1.0000x reference)
//
#include <hip/hip_runtime.h>

#define I_DIMM 256
#define H_DIMM 1024
#define O_DIMM 256
#define S_LENN 512
#define B_SZZ  64
#define SBB    (S_LENN*B_SZZ)      // 32768
#define KTOT   (I_DIMM + H_DIMM)   // 1280
#define KC     128
#define NCHUNK (KTOT/KC)           // 10

__device__ __forceinline__ float sigm(float x){ return 1.f/(1.f+__expf(-x)); }
__device__ __forceinline__ float tanh_fast(float x){
  x = fminf(fmaxf(x,-15.f),15.f);
  float e = __expf(2.f*x);
  return (e-1.f)/(e+1.f);
}

// One LSTM time-step + fc projection of the PREVIOUS step's h.
// grid = 256 blocks x 256 threads. Block bk owns h-indices [bk*4, bk*4+4)
// (16 z-rows = 4 h x 4 gates) over all 64 batch cols, and fc output row o=bk.
__global__ __launch_bounds__(256) void lstm_step_kernel(
    int s,
    const float* __restrict__ X,
    const float* __restrict__ Wf, const float* __restrict__ Wi,
    const float* __restrict__ Wo, const float* __restrict__ Wc,
    const float* __restrict__ Uf, const float* __restrict__ Ui,
    const float* __restrict__ Uo, const float* __restrict__ Uc,
    const float* __restrict__ bf, const float* __restrict__ bi,
    const float* __restrict__ bo, const float* __restrict__ bc,
    const float* __restrict__ fcw, const float* __restrict__ fcb,
    const float* __restrict__ hprev, float* __restrict__ hnext,
    float* __restrict__ cbuf, float* __restrict__ out)
{
  __shared__ float s_xh[KC][B_SZZ];   // 32KB, k-major: [k][b] -> 2-way free
  __shared__ float s_w[16][KC];       // 8KB,  row = h_local*4 + gate
  __shared__ float s_fcw[H_DIMM];     // 4KB
  __shared__ float s_red[4][B_SZZ];   // 1KB

  const int bk = blockIdx.x;
  const int t  = threadIdx.x;
  const int b  = t & 63;
  const int rq = t >> 6;              // 0..3
  const bool do_lstm = (s < S_LENN);
  const bool do_fc   = (s > 0);

  // stage fc weight row o = bk (1024 floats)
  #pragma unroll
  for (int m = 0; m < 4; ++m)
    s_fcw[m*256 + t] = fcw[bk*H_DIMM + m*256 + t];

  float a0=0.f, a1=0.f, a2=0.f, a3=0.f, facc=0.f;

  for (int ch = 0; ch < NCHUNK; ++ch) {
    const int k0 = ch*KC;
    __syncthreads();
    // stage [x;h] chunk: 128 x 64 = 8192 elems, 32/thread, coalesced over b
    #pragma unroll
    for (int m = 0; m < 32; ++m) {
      int idx = m*256 + t;
      int kk = idx >> 6, bb = idx & 63;
      int kg = k0 + kk;
      float v;
      if (kg < I_DIMM) v = do_lstm ? X[kg*SBB + s*B_SZZ + bb] : 0.f;
      else             v = hprev[(kg - I_DIMM)*B_SZZ + bb];
      s_xh[kk][bb] = v;
    }
    if (do_lstm) {
      // stage W tile: 16 rows x 128 k, 8/thread, coalesced within rows
      #pragma unroll
      for (int m = 0; m < 8; ++m) {
        int idx = m*256 + t;
        int row = idx >> 7, kk = idx & 127;
        int kg = k0 + kk;
        int h  = (bk<<2) + (row>>2);
        int g  = row & 3;
        const float* wsrc;
        if (kg < I_DIMM) {
          wsrc = (g==0) ? Wf : (g==1) ? Wi : (g==2) ? Wo : Wc;
          s_w[row][kk] = wsrc[h*I_DIMM + kg];
        } else {
          wsrc = (g==0) ? Uf : (g==1) ? Ui : (g==2) ? Uo : Uc;
          s_w[row][kk] = wsrc[h*H_DIMM + (kg - I_DIMM)];
        }
      }
    }
    __syncthreads();
    if (do_lstm) {
      // thread computes 4 gate rows for h-index bk*4+rq, batch col b
      #pragma unroll 4
      for (int k = 0; k < KC; ++k) {
        float xv = s_xh[k][b];             // 2-way bank alias: free
        a0 += s_w[rq*4+0][k]*xv;           // broadcast rows, b128-mergeable
        a1 += s_w[rq*4+1][k]*xv;
        a2 += s_w[rq*4+2][k]*xv;
        a3 += s_w[rq*4+3][k]*xv;
      }
    }
    if (do_fc && k0 >= I_DIMM) {
      // fc for h_{s-1}: reuse the staged h chunk; thread sums its k-quarter
      const int kb = rq*32;
      const int fo = k0 - I_DIMM;
      #pragma unroll 8
      for (int k = 0; k < 32; ++k)
        facc += s_fcw[fo + kb + k] * s_xh[kb + k][b];
    }
  }

  __syncthreads();
  if (do_fc) s_red[rq][b] = facc;
  __syncthreads();
  if (do_fc && t < B_SZZ) {
    float v = s_red[0][t] + s_red[1][t] + s_red[2][t] + s_red[3][t] + fcb[bk];
    out[bk*SBB + (s-1)*B_SZZ + t] = v;   // logits; softmaxed later in-place
  }

  if (do_lstm) {
    const int h = (bk<<2) + rq;
    float zf = a0 + bf[h];
    float zi = a1 + bi[h];
    float zo = a2 + bo[h];
    float zc = a3 + bc[h];
    float f  = sigm(zf);
    float ig = sigm(zi);
    float og = sigm(zo);
    float ch = tanh_fast(zc);
    float cn = f * cbuf[h*B_SZZ + b] + ig * ch;
    cbuf[h*B_SZZ + b]  = cn;
    hnext[h*B_SZZ + b] = og * tanh_fast(cn);
  }
}

// in-place softmax over o for each (s,b) column; 32768 columns
__global__ __launch_bounds__(256) void softmax_kernel(float* __restrict__ out)
{
  const int col = blockIdx.x*256 + threadIdx.x;   // = s*64 + b, coalesced
  float m = -1e30f, l = 0.f;
  for (int o = 0; o < O_DIMM; ++o) {
    float x  = out[o*SBB + col];
    float mn = fmaxf(m, x);
    l = l*__expf(m - mn) + __expf(x - mn);
    m = mn;
  }
  const float inv = 1.f / l;
  for (int o = 0; o < O_DIMM; ++o) {
    float x = out[o*SBB + col];
    out[o*SBB + col] = __expf(x - m) * inv;
  }
}

__global__ __launch_bounds__(256) void tail_kernel(
    const float* __restrict__ h, const float* __restrict__ c,
    float* __restrict__ out)
{
  const int i = blockIdx.x*256 + threadIdx.x;     // 65536 elems each
  out[O_DIMM*SBB + i]                 = h[i];
  out[O_DIMM*SBB + H_DIMM*B_SZZ + i] = c[i];
}

extern "C" void kernel_launch(void* const* d_in, const int* in_sizes, int n_in,
                              void* d_out, int out_size, void* d_ws, size_t ws_size,
                              hipStream_t stream) {
  const float* X   = (const float*)d_in[0];
  const float* Wf  = (const float*)d_in[1];
  const float* Wi  = (const float*)d_in[2];
  const float* Wo  = (const float*)d_in[3];
  const float* Wc  = (const float*)d_in[4];
  const float* Uf  = (const float*)d_in[5];
  const float* Ui  = (const float*)d_in[6];
  const float* Uo  = (const float*)d_in[7];
  const float* Uc  = (const float*)d_in[8];
  const float* bf  = (const float*)d_in[9];
  const float* bi  = (const float*)d_in[10];
  const float* bo  = (const float*)d_in[11];
  const float* bc  = (const float*)d_in[12];
  const float* fcw = (const float*)d_in[13];
  const float* fcb = (const float*)d_in[14];
  float* out = (float*)d_out;

  float* ws = (float*)d_ws;
  float* h0 = ws;                          // [1024][64]
  float* h1 = ws + H_DIMM*B_SZZ;           // [1024][64]
  float* cb = ws + 2*H_DIMM*B_SZZ;         // [1024][64]

  // ws is re-poisoned 0xAA before every timed call: zero the state each call
  hipMemsetAsync(h0, 0, H_DIMM*B_SZZ*sizeof(float), stream);
  hipMemsetAsync(cb, 0, H_DIMM*B_SZZ*sizeof(float), stream);

  // s = 0..511: LSTM step s (+ fc of h_{s-1} for s>=1); s = 512: fc of h_511
  for (int s = 0; s <= S_LENN; ++s) {
    const float* hp = (s & 1) ? h1 : h0;
    float*       hn = (s & 1) ? h0 : h1;
    lstm_step_kernel<<<256, 256, 0, stream>>>(
        s, X, Wf, Wi, Wo, Wc, Uf, Ui, Uo, Uc,
        bf, bi, bo, bc, fcw, fcb, hp, hn, cb, out);
  }
  softmax_kernel<<<SBB/256, 256, 0, stream>>>(out);
  tail_kernel<<<H_DIMM*B_SZZ/256, 256, 0, stream>>>(h0, cb, out);
}